// Round 25
// baseline (1162.444 us; speedup 1.0000x reference)
//
#include <hip/hip_runtime.h>
#include <hip/hip_fp16.h>

#define DEVI __device__ __forceinline__

typedef short v8s __attribute__((ext_vector_type(8)));
typedef float v4f __attribute__((ext_vector_type(4)));
typedef _Float16 h2v __attribute__((ext_vector_type(2)));
typedef __fp16 fp16x2 __attribute__((ext_vector_type(2)));
typedef unsigned short u16;

typedef __attribute__((address_space(3))) unsigned int lds_u32;
typedef const __attribute__((address_space(1))) unsigned int glb_u32;

DEVI float bf2f(short s) {
  union { unsigned u; float f; } cv;
  cv.u = ((unsigned)(u16)s) << 16;
  return cv.f;
}
DEVI short f2bf(float f) {
  union { float f; unsigned u; } cv; cv.f = f;
  unsigned u = cv.u;
  return (short)((u + 0x7FFFu + ((u >> 16) & 1u)) >> 16);
}
DEVI unsigned cvtpk(float lo, float hi) {  // packed bf16 [hi|lo], RNE (proven R14)
  unsigned r;
  asm("v_cvt_pk_bf16_f32 %0, %1, %2" : "=v"(r) : "v"(lo), "v"(hi));
  return r;
}
DEVI unsigned pkh(float a, float b) {      // packed f16 [b|a], RTZ
  union { fp16x2 h; unsigned u; } cv;
  cv.h = __builtin_amdgcn_cvt_pkrtz(a, b);
  return cv.u;
}
DEVI float fdot2u(unsigned a, unsigned b, float c) {  // f16 dot2, f32 accum (proven R17)
  union { unsigned u; h2v h; } ca, cb; ca.u = a; cb.u = b;
  return __builtin_amdgcn_fdot2(ca.h, cb.h, c, false);
}
DEVI __half2 uh2(unsigned u) { union { unsigned u; __half2 h; } c; c.u = u; return c.h; }
DEVI void gld16(const void* g, void* l) {
  __builtin_amdgcn_global_load_lds((glb_u32*)g, (lds_u32*)l, 16, 0, 0);
}
DEVI float pairsum(float part) {           // part + part[lane^1], via DPP quad_perm
  int o = __builtin_amdgcn_update_dpp(0, __float_as_int(part), 0xB1, 0xf, 0xf, true);
  return part + __int_as_float(o);
}

// ---------------- prep: transpose + cast weights to bf16 ----------------
__global__ void prep_weights(const float* __restrict__ Wq, const float* __restrict__ Wk,
                             const float* __restrict__ Wv, const float* __restrict__ Wout,
                             short* __restrict__ WcT, short* __restrict__ WoT) {
  int n = blockIdx.x;
  int k = threadIdx.x;
  float v;
  if (n < 256)      v = Wq[k * 256 + n];
  else if (n < 512) v = Wk[k * 256 + (n - 256)];
  else              v = Wv[k * 256 + (n - 512)];
  WcT[n * 256 + k] = f2bf(v);
  if (n < 256) WoT[n * 256 + k] = f2bf(Wout[k * 256 + n]);
}

// ---------------- x -> bf16 cast ----------------
__global__ void x_cast(const float* __restrict__ x, short* __restrict__ xb) {
  for (size_t gidx = (size_t)blockIdx.x * 256 + threadIdx.x; gidx < 4194304;
       gidx += (size_t)4096 * 256) {
    const float4* src = reinterpret_cast<const float4*>(x + gidx * 8);
    float4 a = src[0], c = src[1];
    v8s pk;
    pk[0] = f2bf(a.x); pk[1] = f2bf(a.y); pk[2] = f2bf(a.z); pk[3] = f2bf(a.w);
    pk[4] = f2bf(c.x); pk[5] = f2bf(c.y); pk[6] = f2bf(c.z); pk[7] = f2bf(c.w);
    *reinterpret_cast<v8s*>(xb + gidx * 8) = pk;
  }
}

// ---------------- QKV projection: 256x256 tile, swapped-operand MFMA, wide stores ----------------
// Q/K/V all emitted as packed f16 (attn consumes via fdot2 / hfma2).
__launch_bounds__(512, 2)
__global__ void proj_gemm(const short* __restrict__ xb, const short* __restrict__ WcT,
                          const float* __restrict__ pos_emb,
                          short* __restrict__ Qb, short* __restrict__ Kb,
                          short* __restrict__ Vb) {
  __shared__ short As[2][256 * 64];
  __shared__ short Bs[2][256 * 64];
  const int t = threadIdx.x;
  const int bi = blockIdx.x;
  const int xcd = bi & 7;
  const int j = bi >> 3;               // 0..191
  const int mtl = j / 3, nt = j % 3;
  const int mt = xcd * 64 + mtl;       // 0..511, bijective
  const int m0 = mt * 256, n0 = nt * 256;
  const int wave = t >> 6, lane = t & 63;
  const int wm = (wave >> 2) * 128, wn = (wave & 3) * 64;
  const int lr = lane & 15, g = lane >> 4;

  const int ro = lane >> 3;
  const int colb = ((lane & 7) * 16) ^ (ro << 4);
  const char* aSrc0 = reinterpret_cast<const char*>(xb + (size_t)(m0 + ro) * 256) + colb;
  const char* bSrc0 = reinterpret_cast<const char*>(WcT + (size_t)(n0 + ro) * 256) + colb;

  auto stage = [&](int buf, int ks) {
#pragma unroll
    for (int c = 0; c < 4; ++c) {
      int cc = wave * 4 + c;
      gld16(aSrc0 + (size_t)cc * 8 * 512 + ks * 128, (char*)As[buf] + cc * 1024);
      gld16(bSrc0 + (size_t)cc * 8 * 512 + ks * 128, (char*)Bs[buf] + cc * 1024);
    }
  };

  v4f acc[8][4];
#pragma unroll
  for (int i = 0; i < 8; ++i)
#pragma unroll
    for (int jj = 0; jj < 4; ++jj) acc[i][jj] = (v4f){0.f, 0.f, 0.f, 0.f};

  stage(0, 0);
  __syncthreads();

#pragma unroll 1
  for (int s = 0; s < 4; ++s) {
    const int buf = s & 1;
    if (s < 3) stage(buf ^ 1, s + 1);

    const char* aB = (const char*)As[buf];
    const char* bB = (const char*)Bs[buf];
#pragma unroll
    for (int kk = 0; kk < 2; ++kk) {
      v8s bfr[4];
#pragma unroll
      for (int jj = 0; jj < 4; ++jj) {
        int rn = wn + jj * 16 + lr;
        bfr[jj] = *reinterpret_cast<const v8s*>(
            bB + ((rn * 128 + kk * 64 + g * 16) ^ ((rn & 7) << 4)));
      }
#pragma unroll
      for (int i = 0; i < 8; ++i) {
        int row = wm + i * 16 + lr;
        v8s af = *reinterpret_cast<const v8s*>(
            aB + ((row * 128 + kk * 64 + g * 16) ^ ((row & 7) << 4)));
#pragma unroll
        for (int jj = 0; jj < 4; ++jj)
          acc[i][jj] = __builtin_amdgcn_mfma_f32_16x16x32_bf16(bfr[jj], af, acc[i][jj], 0, 0, 0);
      }
    }
    __syncthreads();
  }

  short* dst = (nt == 0) ? Qb : (nt == 1) ? Kb : Vb;
#pragma unroll
  for (int i = 0; i < 8; ++i) {
    int p = m0 + wm + i * 16 + lr;
    int qi = 0;
    if (nt == 0) {
      int yy = (p >> 7) & 127, xx = p & 127;
      qi = (yy - min(max(yy, 2), 125) + 2) * 5 + (xx - min(max(xx, 2), 125) + 2);
    }
#pragma unroll
    for (int jj = 0; jj < 4; ++jj) {
      int nb = wn + jj * 16 + g * 4;
      v4f a = acc[i][jj];
      if (nt == 0) {
        float4 pe4 = *reinterpret_cast<const float4*>(pos_emb + qi * 256 + nb);
        a[0] += pe4.x; a[1] += pe4.y; a[2] += pe4.z; a[3] += pe4.w;
      }
      uint2 pk;
      pk.x = pkh(a[0], a[1]);
      pk.y = pkh(a[2], a[3]);
      *reinterpret_cast<uint2*>(dst + (size_t)p * 256 + nb) = pk;
    }
  }
}

// ---------------- attention: split-F, all-f16, depth-2 prefetch, DPP pair-sum ----------------
__launch_bounds__(256, 6)
__global__ void attn_kernel(const short* __restrict__ Qb, const short* __restrict__ Kb,
                            const short* __restrict__ Vb, const float* __restrict__ pos_emb,
                            short* __restrict__ ACC) {
  __shared__ unsigned pe16[25 * 128];   // packed f16 pairs, word-swizzled (0 conflicts)
  for (int i = threadIdx.x; i < 1600; i += 256) {
    float4 vv = reinterpret_cast<const float4*>(pos_emb)[i];
    int s = i >> 6;
    int jw = (i & 63) * 2;
    int e = ((jw >> 5) & 3) << 1;
    uint2 pk2;
    pk2.x = pkh(vv.x, vv.y);
    pk2.y = pkh(vv.z, vv.w);
    *reinterpret_cast<uint2*>(pe16 + s * 128 + (jw ^ e)) = pk2;
  }

  const int t = threadIdx.x;
  const int half = t & 1, h = (t >> 1) & 7, pl = t >> 4;
  const int id = blockIdx.x;
  const int b = id & 7;
  const int local = id >> 3;
  const int bx = local & 31, by = local >> 5;
  const int xx = bx * 4 + (pl & 3);
  const int yy = by * 4 + (pl >> 2);
  const int yc = min(max(yy, 2), 125), xc = min(max(xx, 2), 125);
  const int fo = h * 32 + half * 16;
  const size_t pbase = ((size_t)((b * 128 + yy) * 128 + xx)) * 256 + fo;
  const size_t cbase = ((size_t)((b * 128 + yc) * 128 + xc)) * 256 + fo;
  const float SCALE2 = 0.17677669529663689f * 1.4426950408889634f;  // rsqrt(32)*log2(e)

  uint4 qA = *reinterpret_cast<const uint4*>(Qb + pbase);
  uint4 qB = *reinterpret_cast<const uint4*>(Qb + pbase + 8);
  __syncthreads();

  float l = 0.f;
  __half2 oa[8];
#pragma unroll
  for (int jv = 0; jv < 8; ++jv) oa[jv] = uh2(0u);

  const short* kb = Kb + cbase;
  const short* vb = Vb + cbase;
  const int sw = h * 16 + half * 8;
  const int e = (h >> 1) << 1;

  // depth-2 prefetch: set a = offset s, set b = offset s+1
  uint4 k0a, k1a, v0a, v1a, k0b, k1b, v0b, v1b;
  {
    const short* kp = kb + (-2 * 128 - 2) * 256;
    const short* vp = vb + (-2 * 128 - 2) * 256;
    k0a = *reinterpret_cast<const uint4*>(kp);
    k1a = *reinterpret_cast<const uint4*>(kp + 8);
    v0a = *reinterpret_cast<const uint4*>(vp);
    v1a = *reinterpret_cast<const uint4*>(vp + 8);
    const short* kp1 = kb + (-2 * 128 - 1) * 256;
    const short* vp1 = vb + (-2 * 128 - 1) * 256;
    k0b = *reinterpret_cast<const uint4*>(kp1);
    k1b = *reinterpret_cast<const uint4*>(kp1 + 8);
    v0b = *reinterpret_cast<const uint4*>(vp1);
    v1b = *reinterpret_cast<const uint4*>(vp1 + 8);
  }

#pragma unroll 1
  for (int dy = -2; dy <= 2; ++dy) {
    const unsigned* prow = pe16 + ((dy + 2) * 5) * 128 + sw;
#pragma unroll
    for (int dxi = 0; dxi < 5; ++dxi) {
      const int dx = dxi - 2;
      uint4 k0 = k0a, k1 = k1a, v0 = v0a, v1 = v1a;
      k0a = k0b; k1a = k1b; v0a = v0b; v1a = v1b;
      int ndx = dx + 2, ndy = dy;
      if (ndx > 2) { ndx -= 5; ndy += 1; }
      if (ndy <= 2) {
        const short* kp2 = kb + (ndy * 128 + ndx) * 256;
        const short* vp2 = vb + (ndy * 128 + ndx) * 256;
        k0b = *reinterpret_cast<const uint4*>(kp2);
        k1b = *reinterpret_cast<const uint4*>(kp2 + 8);
        v0b = *reinterpret_cast<const uint4*>(vp2);
        v1b = *reinterpret_cast<const uint4*>(vp2 + 8);
      }
      const unsigned* ps = prow + dxi * 128;
      uint2 pp0 = *reinterpret_cast<const uint2*>(ps + (0 ^ e));
      uint2 pp1 = *reinterpret_cast<const uint2*>(ps + (2 ^ e));
      uint2 pp2 = *reinterpret_cast<const uint2*>(ps + (4 ^ e));
      uint2 pp3 = *reinterpret_cast<const uint2*>(ps + (6 ^ e));

      float d0 = 0.f, d1 = 0.f, d2 = 0.f, d3 = 0.f;
      d0 = fdot2u(qA.x, k0.x, d0); d1 = fdot2u(qA.y, k0.y, d1);
      d2 = fdot2u(qA.z, k0.z, d2); d3 = fdot2u(qA.w, k0.w, d3);
      d0 = fdot2u(qB.x, k1.x, d0); d1 = fdot2u(qB.y, k1.y, d1);
      d2 = fdot2u(qB.z, k1.z, d2); d3 = fdot2u(qB.w, k1.w, d3);
      d0 = fdot2u(qA.x, pp0.x, d0); d1 = fdot2u(qA.y, pp0.y, d1);
      d2 = fdot2u(qA.z, pp1.x, d2); d3 = fdot2u(qA.w, pp1.y, d3);
      d0 = fdot2u(qB.x, pp2.x, d0); d1 = fdot2u(qB.y, pp2.y, d1);
      d2 = fdot2u(qB.z, pp3.x, d2); d3 = fdot2u(qB.w, pp3.y, d3);

      float part = ((d0 + d1) + (d2 + d3)) * SCALE2;
      float full = pairsum(part);           // DPP quad_perm, no LDS round-trip
      float w = exp2f(full);
      l += w;
      __half2 w2 = uh2(pkh(w, w));
      oa[0] = __hfma2(w2, uh2(v0.x), oa[0]);
      oa[1] = __hfma2(w2, uh2(v0.y), oa[1]);
      oa[2] = __hfma2(w2, uh2(v0.z), oa[2]);
      oa[3] = __hfma2(w2, uh2(v0.w), oa[3]);
      oa[4] = __hfma2(w2, uh2(v1.x), oa[4]);
      oa[5] = __hfma2(w2, uh2(v1.y), oa[5]);
      oa[6] = __hfma2(w2, uh2(v1.z), oa[6]);
      oa[7] = __hfma2(w2, uh2(v1.w), oa[7]);
    }
  }

  float inv = 1.f / l;
  uint4 s0, s1;
  s0.x = cvtpk(__low2float(oa[0]) * inv, __high2float(oa[0]) * inv);
  s0.y = cvtpk(__low2float(oa[1]) * inv, __high2float(oa[1]) * inv);
  s0.z = cvtpk(__low2float(oa[2]) * inv, __high2float(oa[2]) * inv);
  s0.w = cvtpk(__low2float(oa[3]) * inv, __high2float(oa[3]) * inv);
  s1.x = cvtpk(__low2float(oa[4]) * inv, __high2float(oa[4]) * inv);
  s1.y = cvtpk(__low2float(oa[5]) * inv, __high2float(oa[5]) * inv);
  s1.z = cvtpk(__low2float(oa[6]) * inv, __high2float(oa[6]) * inv);
  s1.w = cvtpk(__low2float(oa[7]) * inv, __high2float(oa[7]) * inv);
  *reinterpret_cast<uint4*>(ACC + pbase) = s0;
  *reinterpret_cast<uint4*>(ACC + pbase + 8) = s1;
}

// ---------------- output projection: 256x256 tile, swapped operands, float4 stores ----------------
__launch_bounds__(512, 2)
__global__ void out_gemm(const short* __restrict__ A, const short* __restrict__ WoT,
                         float* __restrict__ out) {
  __shared__ short As[2][256 * 64];
  __shared__ short Bs[2][256 * 64];
  const int t = threadIdx.x;
  const int bi = blockIdx.x;
  const int xcd = bi & 7;
  const int mt = xcd * 64 + (bi >> 3);
  const int m0 = mt * 256;
  const int wave = t >> 6, lane = t & 63;
  const int wm = (wave >> 2) * 128, wn = (wave & 3) * 64;
  const int lr = lane & 15, g = lane >> 4;

  const int ro = lane >> 3;
  const int colb = ((lane & 7) * 16) ^ (ro << 4);
  const char* aSrc0 = reinterpret_cast<const char*>(A + (size_t)(m0 + ro) * 256) + colb;
  const char* bSrc0 = reinterpret_cast<const char*>(WoT + (size_t)ro * 256) + colb;

  auto stage = [&](int buf, int ks) {
#pragma unroll
    for (int c = 0; c < 4; ++c) {
      int cc = wave * 4 + c;
      gld16(aSrc0 + (size_t)cc * 8 * 512 + ks * 128, (char*)As[buf] + cc * 1024);
      gld16(bSrc0 + (size_t)cc * 8 * 512 + ks * 128, (char*)Bs[buf] + cc * 1024);
    }
  };

  v4f acc[8][4];
#pragma unroll
  for (int i = 0; i < 8; ++i)
#pragma unroll
    for (int jj = 0; jj < 4; ++jj) acc[i][jj] = (v4f){0.f, 0.f, 0.f, 0.f};

  stage(0, 0);
  __syncthreads();

#pragma unroll 1
  for (int s = 0; s < 4; ++s) {
    const int buf = s & 1;
    if (s < 3) stage(buf ^ 1, s + 1);

    const char* aB = (const char*)As[buf];
    const char* bB = (const char*)Bs[buf];
#pragma unroll
    for (int kk = 0; kk < 2; ++kk) {
      v8s bfr[4];
#pragma unroll
      for (int jj = 0; jj < 4; ++jj) {
        int rn = wn + jj * 16 + lr;
        bfr[jj] = *reinterpret_cast<const v8s*>(
            bB + ((rn * 128 + kk * 64 + g * 16) ^ ((rn & 7) << 4)));
      }
#pragma unroll
      for (int i = 0; i < 8; ++i) {
        int row = wm + i * 16 + lr;
        v8s af = *reinterpret_cast<const v8s*>(
            aB + ((row * 128 + kk * 64 + g * 16) ^ ((row & 7) << 4)));
#pragma unroll
        for (int jj = 0; jj < 4; ++jj)
          acc[i][jj] = __builtin_amdgcn_mfma_f32_16x16x32_bf16(bfr[jj], af, acc[i][jj], 0, 0, 0);
      }
    }
    __syncthreads();
  }

#pragma unroll
  for (int i = 0; i < 8; ++i) {
    int p = m0 + wm + i * 16 + lr;
#pragma unroll
    for (int jj = 0; jj < 4; ++jj) {
      int nb = wn + jj * 16 + g * 4;
      float4 o;
      o.x = acc[i][jj][0]; o.y = acc[i][jj][1];
      o.z = acc[i][jj][2]; o.w = acc[i][jj][3];
      *reinterpret_cast<float4*>(out + (size_t)p * 256 + nb) = o;
    }
  }
}

extern "C" void kernel_launch(void* const* d_in, const int* in_sizes, int n_in,
                              void* d_out, int out_size, void* d_ws, size_t ws_size,
                              hipStream_t stream) {
  const float* x       = (const float*)d_in[0];
  const float* Wq      = (const float*)d_in[1];
  const float* Wk      = (const float*)d_in[2];
  const float* Wv      = (const float*)d_in[3];
  const float* Wout    = (const float*)d_in[4];
  const float* pos_emb = (const float*)d_in[5];
  float* out = (float*)d_out;

  char* ws = (char*)d_ws;
  short* WcT  = (short*)ws;                       // 768*256*2   = 393216 B
  short* WoT  = (short*)(ws + 393216);            // 256*256*2   = 131072 B
  short* Qb   = (short*)(ws + 524288);            // 131072*256*2 each
  short* Kb   = Qb + (size_t)131072 * 256;
  short* Vb   = Kb + (size_t)131072 * 256;
  short* ACCb = Vb + (size_t)131072 * 256;
  short* xb   = ACCb;   // alias: xb used only before attn writes ACCb

  prep_weights<<<768, 256, 0, stream>>>(Wq, Wk, Wv, Wout, WcT, WoT);
  x_cast<<<4096, 256, 0, stream>>>(x, xb);
  proj_gemm<<<1536, 512, 0, stream>>>(xb, WcT, pos_emb, Qb, Kb, Vb);
  attn_kernel<<<8192, 256, 0, stream>>>(Qb, Kb, Vb, pos_emb, ACCb);
  out_gemm<<<512, 512, 0, stream>>>(ACCb, WoT, out);
}

// Round 26
// 326.008 us; speedup vs baseline: 3.5657x; 3.5657x over previous
//
#include <hip/hip_runtime.h>
#include <hip/hip_fp16.h>

#define DEVI __device__ __forceinline__

typedef short v8s __attribute__((ext_vector_type(8)));
typedef float v4f __attribute__((ext_vector_type(4)));
typedef _Float16 h2v __attribute__((ext_vector_type(2)));
typedef __fp16 fp16x2 __attribute__((ext_vector_type(2)));
typedef unsigned short u16;

typedef __attribute__((address_space(3))) unsigned int lds_u32;
typedef const __attribute__((address_space(1))) unsigned int glb_u32;

DEVI float bf2f(short s) {
  union { unsigned u; float f; } cv;
  cv.u = ((unsigned)(u16)s) << 16;
  return cv.f;
}
DEVI short f2bf(float f) {
  union { float f; unsigned u; } cv; cv.f = f;
  unsigned u = cv.u;
  return (short)((u + 0x7FFFu + ((u >> 16) & 1u)) >> 16);
}
DEVI unsigned cvtpk(float lo, float hi) {  // packed bf16 [hi|lo], RNE (proven R14)
  unsigned r;
  asm("v_cvt_pk_bf16_f32 %0, %1, %2" : "=v"(r) : "v"(lo), "v"(hi));
  return r;
}
DEVI unsigned pkh(float a, float b) {      // packed f16 [b|a], RTZ
  union { fp16x2 h; unsigned u; } cv;
  cv.h = __builtin_amdgcn_cvt_pkrtz(a, b);
  return cv.u;
}
DEVI float fdot2u(unsigned a, unsigned b, float c) {  // f16 dot2, f32 accum (proven R17)
  union { unsigned u; h2v h; } ca, cb; ca.u = a; cb.u = b;
  return __builtin_amdgcn_fdot2(ca.h, cb.h, c, false);
}
DEVI __half2 uh2(unsigned u) { union { unsigned u; __half2 h; } c; c.u = u; return c.h; }
DEVI void gld16(const void* g, void* l) {
  __builtin_amdgcn_global_load_lds((glb_u32*)g, (lds_u32*)l, 16, 0, 0);
}
DEVI float pairsum(float part) {           // part + part[lane^1], via DPP quad_perm
  int o = __builtin_amdgcn_update_dpp(0, __float_as_int(part), 0xB1, 0xf, 0xf, true);
  return part + __int_as_float(o);
}

// ---------------- prep: transpose + cast weights to bf16 ----------------
__global__ void prep_weights(const float* __restrict__ Wq, const float* __restrict__ Wk,
                             const float* __restrict__ Wv, const float* __restrict__ Wout,
                             short* __restrict__ WcT, short* __restrict__ WoT) {
  int n = blockIdx.x;
  int k = threadIdx.x;
  float v;
  if (n < 256)      v = Wq[k * 256 + n];
  else if (n < 512) v = Wk[k * 256 + (n - 256)];
  else              v = Wv[k * 256 + (n - 512)];
  WcT[n * 256 + k] = f2bf(v);
  if (n < 256) WoT[n * 256 + k] = f2bf(Wout[k * 256 + n]);
}

// ---------------- x -> bf16 cast ----------------
__global__ void x_cast(const float* __restrict__ x, short* __restrict__ xb) {
  for (size_t gidx = (size_t)blockIdx.x * 256 + threadIdx.x; gidx < 4194304;
       gidx += (size_t)4096 * 256) {
    const float4* src = reinterpret_cast<const float4*>(x + gidx * 8);
    float4 a = src[0], c = src[1];
    v8s pk;
    pk[0] = f2bf(a.x); pk[1] = f2bf(a.y); pk[2] = f2bf(a.z); pk[3] = f2bf(a.w);
    pk[4] = f2bf(c.x); pk[5] = f2bf(c.y); pk[6] = f2bf(c.z); pk[7] = f2bf(c.w);
    *reinterpret_cast<v8s*>(xb + gidx * 8) = pk;
  }
}

// ---------------- QKV projection: 256x256 tile, swapped-operand MFMA, wide stores ----------------
// Q/K/V all emitted as packed f16 (attn consumes via fdot2 / hfma2).
__launch_bounds__(512, 2)
__global__ void proj_gemm(const short* __restrict__ xb, const short* __restrict__ WcT,
                          const float* __restrict__ pos_emb,
                          short* __restrict__ Qb, short* __restrict__ Kb,
                          short* __restrict__ Vb) {
  __shared__ short As[2][256 * 64];
  __shared__ short Bs[2][256 * 64];
  const int t = threadIdx.x;
  const int bi = blockIdx.x;
  const int xcd = bi & 7;
  const int j = bi >> 3;               // 0..191
  const int mtl = j / 3, nt = j % 3;
  const int mt = xcd * 64 + mtl;       // 0..511, bijective
  const int m0 = mt * 256, n0 = nt * 256;
  const int wave = t >> 6, lane = t & 63;
  const int wm = (wave >> 2) * 128, wn = (wave & 3) * 64;
  const int lr = lane & 15, g = lane >> 4;

  const int ro = lane >> 3;
  const int colb = ((lane & 7) * 16) ^ (ro << 4);
  const char* aSrc0 = reinterpret_cast<const char*>(xb + (size_t)(m0 + ro) * 256) + colb;
  const char* bSrc0 = reinterpret_cast<const char*>(WcT + (size_t)(n0 + ro) * 256) + colb;

  auto stage = [&](int buf, int ks) {
#pragma unroll
    for (int c = 0; c < 4; ++c) {
      int cc = wave * 4 + c;
      gld16(aSrc0 + (size_t)cc * 8 * 512 + ks * 128, (char*)As[buf] + cc * 1024);
      gld16(bSrc0 + (size_t)cc * 8 * 512 + ks * 128, (char*)Bs[buf] + cc * 1024);
    }
  };

  v4f acc[8][4];
#pragma unroll
  for (int i = 0; i < 8; ++i)
#pragma unroll
    for (int jj = 0; jj < 4; ++jj) acc[i][jj] = (v4f){0.f, 0.f, 0.f, 0.f};

  stage(0, 0);
  __syncthreads();

#pragma unroll 1
  for (int s = 0; s < 4; ++s) {
    const int buf = s & 1;
    if (s < 3) stage(buf ^ 1, s + 1);

    const char* aB = (const char*)As[buf];
    const char* bB = (const char*)Bs[buf];
#pragma unroll
    for (int kk = 0; kk < 2; ++kk) {
      v8s bfr[4];
#pragma unroll
      for (int jj = 0; jj < 4; ++jj) {
        int rn = wn + jj * 16 + lr;
        bfr[jj] = *reinterpret_cast<const v8s*>(
            bB + ((rn * 128 + kk * 64 + g * 16) ^ ((rn & 7) << 4)));
      }
#pragma unroll
      for (int i = 0; i < 8; ++i) {
        int row = wm + i * 16 + lr;
        v8s af = *reinterpret_cast<const v8s*>(
            aB + ((row * 128 + kk * 64 + g * 16) ^ ((row & 7) << 4)));
#pragma unroll
        for (int jj = 0; jj < 4; ++jj)
          acc[i][jj] = __builtin_amdgcn_mfma_f32_16x16x32_bf16(bfr[jj], af, acc[i][jj], 0, 0, 0);
      }
    }
    __syncthreads();
  }

  short* dst = (nt == 0) ? Qb : (nt == 1) ? Kb : Vb;
#pragma unroll
  for (int i = 0; i < 8; ++i) {
    int p = m0 + wm + i * 16 + lr;
    int qi = 0;
    if (nt == 0) {
      int yy = (p >> 7) & 127, xx = p & 127;
      qi = (yy - min(max(yy, 2), 125) + 2) * 5 + (xx - min(max(xx, 2), 125) + 2);
    }
#pragma unroll
    for (int jj = 0; jj < 4; ++jj) {
      int nb = wn + jj * 16 + g * 4;
      v4f a = acc[i][jj];
      if (nt == 0) {
        float4 pe4 = *reinterpret_cast<const float4*>(pos_emb + qi * 256 + nb);
        a[0] += pe4.x; a[1] += pe4.y; a[2] += pe4.z; a[3] += pe4.w;
      }
      uint2 pk;
      pk.x = pkh(a[0], a[1]);
      pk.y = pkh(a[2], a[3]);
      *reinterpret_cast<uint2*>(dst + (size_t)p * 256 + nb) = pk;
    }
  }
}

// ---------------- attention: split-F, all-f16, depth-2 prefetch, DPP pair-sum ----------------
__launch_bounds__(256, 4)
__global__ void attn_kernel(const short* __restrict__ Qb, const short* __restrict__ Kb,
                            const short* __restrict__ Vb, const float* __restrict__ pos_emb,
                            short* __restrict__ ACC) {
  __shared__ unsigned pe16[25 * 128];   // packed f16 pairs, word-swizzled (0 conflicts)
  for (int i = threadIdx.x; i < 1600; i += 256) {
    float4 vv = reinterpret_cast<const float4*>(pos_emb)[i];
    int s = i >> 6;
    int jw = (i & 63) * 2;
    int e = ((jw >> 5) & 3) << 1;
    uint2 pk2;
    pk2.x = pkh(vv.x, vv.y);
    pk2.y = pkh(vv.z, vv.w);
    *reinterpret_cast<uint2*>(pe16 + s * 128 + (jw ^ e)) = pk2;
  }

  const int t = threadIdx.x;
  const int half = t & 1, h = (t >> 1) & 7, pl = t >> 4;
  const int id = blockIdx.x;
  const int b = id & 7;
  const int local = id >> 3;
  const int bx = local & 31, by = local >> 5;
  const int xx = bx * 4 + (pl & 3);
  const int yy = by * 4 + (pl >> 2);
  const int yc = min(max(yy, 2), 125), xc = min(max(xx, 2), 125);
  const int fo = h * 32 + half * 16;
  const size_t pbase = ((size_t)((b * 128 + yy) * 128 + xx)) * 256 + fo;
  const size_t cbase = ((size_t)((b * 128 + yc) * 128 + xc)) * 256 + fo;
  const float SCALE2 = 0.17677669529663689f * 1.4426950408889634f;  // rsqrt(32)*log2(e)

  uint4 qA = *reinterpret_cast<const uint4*>(Qb + pbase);
  uint4 qB = *reinterpret_cast<const uint4*>(Qb + pbase + 8);
  __syncthreads();

  float l = 0.f;
  __half2 oa[8];
#pragma unroll
  for (int jv = 0; jv < 8; ++jv) oa[jv] = uh2(0u);

  const short* kb = Kb + cbase;
  const short* vb = Vb + cbase;
  const int sw = h * 16 + half * 8;
  const int e = (h >> 1) << 1;

  // depth-2 prefetch: set a = offset s, set b = offset s+1
  uint4 k0a, k1a, v0a, v1a, k0b, k1b, v0b, v1b;
  {
    const short* kp = kb + (-2 * 128 - 2) * 256;
    const short* vp = vb + (-2 * 128 - 2) * 256;
    k0a = *reinterpret_cast<const uint4*>(kp);
    k1a = *reinterpret_cast<const uint4*>(kp + 8);
    v0a = *reinterpret_cast<const uint4*>(vp);
    v1a = *reinterpret_cast<const uint4*>(vp + 8);
    const short* kp1 = kb + (-2 * 128 - 1) * 256;
    const short* vp1 = vb + (-2 * 128 - 1) * 256;
    k0b = *reinterpret_cast<const uint4*>(kp1);
    k1b = *reinterpret_cast<const uint4*>(kp1 + 8);
    v0b = *reinterpret_cast<const uint4*>(vp1);
    v1b = *reinterpret_cast<const uint4*>(vp1 + 8);
  }

#pragma unroll 1
  for (int dy = -2; dy <= 2; ++dy) {
    const unsigned* prow = pe16 + ((dy + 2) * 5) * 128 + sw;
#pragma unroll
    for (int dxi = 0; dxi < 5; ++dxi) {
      const int dx = dxi - 2;
      uint4 k0 = k0a, k1 = k1a, v0 = v0a, v1 = v1a;
      k0a = k0b; k1a = k1b; v0a = v0b; v1a = v1b;
      int ndx = dx + 2, ndy = dy;
      if (ndx > 2) { ndx -= 5; ndy += 1; }
      if (ndy <= 2) {
        const short* kp2 = kb + (ndy * 128 + ndx) * 256;
        const short* vp2 = vb + (ndy * 128 + ndx) * 256;
        k0b = *reinterpret_cast<const uint4*>(kp2);
        k1b = *reinterpret_cast<const uint4*>(kp2 + 8);
        v0b = *reinterpret_cast<const uint4*>(vp2);
        v1b = *reinterpret_cast<const uint4*>(vp2 + 8);
      }
      const unsigned* ps = prow + dxi * 128;
      uint2 pp0 = *reinterpret_cast<const uint2*>(ps + (0 ^ e));
      uint2 pp1 = *reinterpret_cast<const uint2*>(ps + (2 ^ e));
      uint2 pp2 = *reinterpret_cast<const uint2*>(ps + (4 ^ e));
      uint2 pp3 = *reinterpret_cast<const uint2*>(ps + (6 ^ e));

      float d0 = 0.f, d1 = 0.f, d2 = 0.f, d3 = 0.f;
      d0 = fdot2u(qA.x, k0.x, d0); d1 = fdot2u(qA.y, k0.y, d1);
      d2 = fdot2u(qA.z, k0.z, d2); d3 = fdot2u(qA.w, k0.w, d3);
      d0 = fdot2u(qB.x, k1.x, d0); d1 = fdot2u(qB.y, k1.y, d1);
      d2 = fdot2u(qB.z, k1.z, d2); d3 = fdot2u(qB.w, k1.w, d3);
      d0 = fdot2u(qA.x, pp0.x, d0); d1 = fdot2u(qA.y, pp0.y, d1);
      d2 = fdot2u(qA.z, pp1.x, d2); d3 = fdot2u(qA.w, pp1.y, d3);
      d0 = fdot2u(qB.x, pp2.x, d0); d1 = fdot2u(qB.y, pp2.y, d1);
      d2 = fdot2u(qB.z, pp3.x, d2); d3 = fdot2u(qB.w, pp3.y, d3);

      float part = ((d0 + d1) + (d2 + d3)) * SCALE2;
      float full = pairsum(part);           // DPP quad_perm, no LDS round-trip
      float w = exp2f(full);
      l += w;
      __half2 w2 = uh2(pkh(w, w));
      oa[0] = __hfma2(w2, uh2(v0.x), oa[0]);
      oa[1] = __hfma2(w2, uh2(v0.y), oa[1]);
      oa[2] = __hfma2(w2, uh2(v0.z), oa[2]);
      oa[3] = __hfma2(w2, uh2(v0.w), oa[3]);
      oa[4] = __hfma2(w2, uh2(v1.x), oa[4]);
      oa[5] = __hfma2(w2, uh2(v1.y), oa[5]);
      oa[6] = __hfma2(w2, uh2(v1.z), oa[6]);
      oa[7] = __hfma2(w2, uh2(v1.w), oa[7]);
    }
  }

  float inv = 1.f / l;
  uint4 s0, s1;
  s0.x = cvtpk(__low2float(oa[0]) * inv, __high2float(oa[0]) * inv);
  s0.y = cvtpk(__low2float(oa[1]) * inv, __high2float(oa[1]) * inv);
  s0.z = cvtpk(__low2float(oa[2]) * inv, __high2float(oa[2]) * inv);
  s0.w = cvtpk(__low2float(oa[3]) * inv, __high2float(oa[3]) * inv);
  s1.x = cvtpk(__low2float(oa[4]) * inv, __high2float(oa[4]) * inv);
  s1.y = cvtpk(__low2float(oa[5]) * inv, __high2float(oa[5]) * inv);
  s1.z = cvtpk(__low2float(oa[6]) * inv, __high2float(oa[6]) * inv);
  s1.w = cvtpk(__low2float(oa[7]) * inv, __high2float(oa[7]) * inv);
  *reinterpret_cast<uint4*>(ACC + pbase) = s0;
  *reinterpret_cast<uint4*>(ACC + pbase + 8) = s1;
}

// ---------------- output projection: 256x256 tile, swapped operands, float4 stores ----------------
__launch_bounds__(512, 2)
__global__ void out_gemm(const short* __restrict__ A, const short* __restrict__ WoT,
                         float* __restrict__ out) {
  __shared__ short As[2][256 * 64];
  __shared__ short Bs[2][256 * 64];
  const int t = threadIdx.x;
  const int bi = blockIdx.x;
  const int xcd = bi & 7;
  const int mt = xcd * 64 + (bi >> 3);
  const int m0 = mt * 256;
  const int wave = t >> 6, lane = t & 63;
  const int wm = (wave >> 2) * 128, wn = (wave & 3) * 64;
  const int lr = lane & 15, g = lane >> 4;

  const int ro = lane >> 3;
  const int colb = ((lane & 7) * 16) ^ (ro << 4);
  const char* aSrc0 = reinterpret_cast<const char*>(A + (size_t)(m0 + ro) * 256) + colb;
  const char* bSrc0 = reinterpret_cast<const char*>(WoT + (size_t)ro * 256) + colb;

  auto stage = [&](int buf, int ks) {
#pragma unroll
    for (int c = 0; c < 4; ++c) {
      int cc = wave * 4 + c;
      gld16(aSrc0 + (size_t)cc * 8 * 512 + ks * 128, (char*)As[buf] + cc * 1024);
      gld16(bSrc0 + (size_t)cc * 8 * 512 + ks * 128, (char*)Bs[buf] + cc * 1024);
    }
  };

  v4f acc[8][4];
#pragma unroll
  for (int i = 0; i < 8; ++i)
#pragma unroll
    for (int jj = 0; jj < 4; ++jj) acc[i][jj] = (v4f){0.f, 0.f, 0.f, 0.f};

  stage(0, 0);
  __syncthreads();

#pragma unroll 1
  for (int s = 0; s < 4; ++s) {
    const int buf = s & 1;
    if (s < 3) stage(buf ^ 1, s + 1);

    const char* aB = (const char*)As[buf];
    const char* bB = (const char*)Bs[buf];
#pragma unroll
    for (int kk = 0; kk < 2; ++kk) {
      v8s bfr[4];
#pragma unroll
      for (int jj = 0; jj < 4; ++jj) {
        int rn = wn + jj * 16 + lr;
        bfr[jj] = *reinterpret_cast<const v8s*>(
            bB + ((rn * 128 + kk * 64 + g * 16) ^ ((rn & 7) << 4)));
      }
#pragma unroll
      for (int i = 0; i < 8; ++i) {
        int row = wm + i * 16 + lr;
        v8s af = *reinterpret_cast<const v8s*>(
            aB + ((row * 128 + kk * 64 + g * 16) ^ ((row & 7) << 4)));
#pragma unroll
        for (int jj = 0; jj < 4; ++jj)
          acc[i][jj] = __builtin_amdgcn_mfma_f32_16x16x32_bf16(bfr[jj], af, acc[i][jj], 0, 0, 0);
      }
    }
    __syncthreads();
  }

#pragma unroll
  for (int i = 0; i < 8; ++i) {
    int p = m0 + wm + i * 16 + lr;
#pragma unroll
    for (int jj = 0; jj < 4; ++jj) {
      int nb = wn + jj * 16 + g * 4;
      float4 o;
      o.x = acc[i][jj][0]; o.y = acc[i][jj][1];
      o.z = acc[i][jj][2]; o.w = acc[i][jj][3];
      *reinterpret_cast<float4*>(out + (size_t)p * 256 + nb) = o;
    }
  }
}

extern "C" void kernel_launch(void* const* d_in, const int* in_sizes, int n_in,
                              void* d_out, int out_size, void* d_ws, size_t ws_size,
                              hipStream_t stream) {
  const float* x       = (const float*)d_in[0];
  const float* Wq      = (const float*)d_in[1];
  const float* Wk      = (const float*)d_in[2];
  const float* Wv      = (const float*)d_in[3];
  const float* Wout    = (const float*)d_in[4];
  const float* pos_emb = (const float*)d_in[5];
  float* out = (float*)d_out;

  char* ws = (char*)d_ws;
  short* WcT  = (short*)ws;                       // 768*256*2   = 393216 B
  short* WoT  = (short*)(ws + 393216);            // 256*256*2   = 131072 B
  short* Qb   = (short*)(ws + 524288);            // 131072*256*2 each
  short* Kb   = Qb + (size_t)131072 * 256;
  short* Vb   = Kb + (size_t)131072 * 256;
  short* ACCb = Vb + (size_t)131072 * 256;
  short* xb   = ACCb;   // alias: xb used only before attn writes ACCb

  prep_weights<<<768, 256, 0, stream>>>(Wq, Wk, Wv, Wout, WcT, WoT);
  x_cast<<<4096, 256, 0, stream>>>(x, xb);
  proj_gemm<<<1536, 512, 0, stream>>>(xb, WcT, pos_emb, Qb, Kb, Vb);
  attn_kernel<<<8192, 256, 0, stream>>>(Qb, Kb, Vb, pos_emb, ACCb);
  out_gemm<<<512, 512, 0, stream>>>(ACCb, WoT, out);
}

// Round 27
// 322.366 us; speedup vs baseline: 3.6060x; 1.0113x over previous
//
#include <hip/hip_runtime.h>
#include <hip/hip_fp16.h>

#define DEVI __device__ __forceinline__

typedef short v8s __attribute__((ext_vector_type(8)));
typedef float v4f __attribute__((ext_vector_type(4)));
typedef _Float16 h2v __attribute__((ext_vector_type(2)));
typedef __fp16 fp16x2 __attribute__((ext_vector_type(2)));
typedef unsigned short u16;

typedef __attribute__((address_space(3))) unsigned int lds_u32;
typedef const __attribute__((address_space(1))) unsigned int glb_u32;

DEVI float bf2f(short s) {
  union { unsigned u; float f; } cv;
  cv.u = ((unsigned)(u16)s) << 16;
  return cv.f;
}
DEVI short f2bf(float f) {
  union { float f; unsigned u; } cv; cv.f = f;
  unsigned u = cv.u;
  return (short)((u + 0x7FFFu + ((u >> 16) & 1u)) >> 16);
}
DEVI unsigned cvtpk(float lo, float hi) {  // packed bf16 [hi|lo], RNE (proven R14)
  unsigned r;
  asm("v_cvt_pk_bf16_f32 %0, %1, %2" : "=v"(r) : "v"(lo), "v"(hi));
  return r;
}
DEVI unsigned pkh(float a, float b) {      // packed f16 [b|a], RTZ
  union { fp16x2 h; unsigned u; } cv;
  cv.h = __builtin_amdgcn_cvt_pkrtz(a, b);
  return cv.u;
}
DEVI float fdot2u(unsigned a, unsigned b, float c) {  // f16 dot2, f32 accum (proven R17)
  union { unsigned u; h2v h; } ca, cb; ca.u = a; cb.u = b;
  return __builtin_amdgcn_fdot2(ca.h, cb.h, c, false);
}
DEVI __half2 uh2(unsigned u) { union { unsigned u; __half2 h; } c; c.u = u; return c.h; }
DEVI void gld16(const void* g, void* l) {
  __builtin_amdgcn_global_load_lds((glb_u32*)g, (lds_u32*)l, 16, 0, 0);
}
DEVI float pairsum(float part) {           // part + part[lane^1], via DPP quad_perm
  int o = __builtin_amdgcn_update_dpp(0, __float_as_int(part), 0xB1, 0xf, 0xf, true);
  return part + __int_as_float(o);
}
#define SBAR() __builtin_amdgcn_s_barrier()
#define SCHED0() __builtin_amdgcn_sched_barrier(0)

// ---------------- prep: transpose + cast weights to bf16 ----------------
__global__ void prep_weights(const float* __restrict__ Wq, const float* __restrict__ Wk,
                             const float* __restrict__ Wv, const float* __restrict__ Wout,
                             short* __restrict__ WcT, short* __restrict__ WoT) {
  int n = blockIdx.x;
  int k = threadIdx.x;
  float v;
  if (n < 256)      v = Wq[k * 256 + n];
  else if (n < 512) v = Wk[k * 256 + (n - 256)];
  else              v = Wv[k * 256 + (n - 512)];
  WcT[n * 256 + k] = f2bf(v);
  if (n < 256) WoT[n * 256 + k] = f2bf(Wout[k * 256 + n]);
}

// ---------------- x -> bf16 cast ----------------
__global__ void x_cast(const float* __restrict__ x, short* __restrict__ xb) {
  for (size_t gidx = (size_t)blockIdx.x * 256 + threadIdx.x; gidx < 4194304;
       gidx += (size_t)4096 * 256) {
    const float4* src = reinterpret_cast<const float4*>(x + gidx * 8);
    float4 a = src[0], c = src[1];
    v8s pk;
    pk[0] = f2bf(a.x); pk[1] = f2bf(a.y); pk[2] = f2bf(a.z); pk[3] = f2bf(a.w);
    pk[4] = f2bf(c.x); pk[5] = f2bf(c.y); pk[6] = f2bf(c.z); pk[7] = f2bf(c.w);
    *reinterpret_cast<v8s*>(xb + gidx * 8) = pk;
  }
}

// ---------------- QKV projection: 256x256 tile + counted-vmcnt pipeline ----------------
// Per step: stage(s+1) stays in flight across the barrier; wait only stage(s) (aged ~614cy).
__launch_bounds__(512, 2)
__global__ void proj_gemm(const short* __restrict__ xb, const short* __restrict__ WcT,
                          const float* __restrict__ pos_emb,
                          short* __restrict__ Qb, short* __restrict__ Kb,
                          short* __restrict__ Vb) {
  __shared__ short As[2][256 * 64];
  __shared__ short Bs[2][256 * 64];
  const int t = threadIdx.x;
  const int bi = blockIdx.x;
  const int xcd = bi & 7;
  const int j = bi >> 3;               // 0..191
  const int mtl = j / 3, nt = j % 3;
  const int mt = xcd * 64 + mtl;       // 0..511, bijective
  const int m0 = mt * 256, n0 = nt * 256;
  const int wave = t >> 6, lane = t & 63;
  const int wm = (wave >> 2) * 128, wn = (wave & 3) * 64;
  const int lr = lane & 15, g = lane >> 4;

  const int ro = lane >> 3;
  const int colb = ((lane & 7) * 16) ^ (ro << 4);
  const char* aSrc0 = reinterpret_cast<const char*>(xb + (size_t)(m0 + ro) * 256) + colb;
  const char* bSrc0 = reinterpret_cast<const char*>(WcT + (size_t)(n0 + ro) * 256) + colb;

  auto stage = [&](int buf, int ks) {
#pragma unroll
    for (int c = 0; c < 4; ++c) {
      int cc = wave * 4 + c;
      gld16(aSrc0 + (size_t)cc * 8 * 512 + ks * 128, (char*)As[buf] + cc * 1024);
      gld16(bSrc0 + (size_t)cc * 8 * 512 + ks * 128, (char*)Bs[buf] + cc * 1024);
    }
  };

  v4f acc[8][4];
#pragma unroll
  for (int i = 0; i < 8; ++i)
#pragma unroll
    for (int jj = 0; jj < 4; ++jj) acc[i][jj] = (v4f){0.f, 0.f, 0.f, 0.f};

  stage(0, 0);

#pragma unroll 1
  for (int s = 0; s < 4; ++s) {
    const int buf = s & 1;
    if (s < 3) {
      stage(buf ^ 1, s + 1);
      asm volatile("s_waitcnt vmcnt(8)" ::: "memory");  // stage(s) landed; stage(s+1) in flight
    } else {
      asm volatile("s_waitcnt vmcnt(0)" ::: "memory");  // stage(3), aged a full compute phase
    }
    SBAR();
    SCHED0();

    const char* aB = (const char*)As[buf];
    const char* bB = (const char*)Bs[buf];
#pragma unroll
    for (int kk = 0; kk < 2; ++kk) {
      v8s bfr[4];
#pragma unroll
      for (int jj = 0; jj < 4; ++jj) {
        int rn = wn + jj * 16 + lr;
        bfr[jj] = *reinterpret_cast<const v8s*>(
            bB + ((rn * 128 + kk * 64 + g * 16) ^ ((rn & 7) << 4)));
      }
#pragma unroll
      for (int i = 0; i < 8; ++i) {
        int row = wm + i * 16 + lr;
        v8s af = *reinterpret_cast<const v8s*>(
            aB + ((row * 128 + kk * 64 + g * 16) ^ ((row & 7) << 4)));
#pragma unroll
        for (int jj = 0; jj < 4; ++jj)
          acc[i][jj] = __builtin_amdgcn_mfma_f32_16x16x32_bf16(bfr[jj], af, acc[i][jj], 0, 0, 0);
      }
    }
    if (s < 3) {
      asm volatile("s_waitcnt lgkmcnt(0)" ::: "memory");
      SBAR();            // buffer handoff: all waves done reading buf before its re-stage
      SCHED0();
    }
  }

  short* dst = (nt == 0) ? Qb : (nt == 1) ? Kb : Vb;
#pragma unroll
  for (int i = 0; i < 8; ++i) {
    int p = m0 + wm + i * 16 + lr;
    int qi = 0;
    if (nt == 0) {
      int yy = (p >> 7) & 127, xx = p & 127;
      qi = (yy - min(max(yy, 2), 125) + 2) * 5 + (xx - min(max(xx, 2), 125) + 2);
    }
#pragma unroll
    for (int jj = 0; jj < 4; ++jj) {
      int nb = wn + jj * 16 + g * 4;
      v4f a = acc[i][jj];
      if (nt == 0) {
        float4 pe4 = *reinterpret_cast<const float4*>(pos_emb + qi * 256 + nb);
        a[0] += pe4.x; a[1] += pe4.y; a[2] += pe4.z; a[3] += pe4.w;
      }
      uint2 pk;
      pk.x = pkh(a[0], a[1]);
      pk.y = pkh(a[2], a[3]);
      *reinterpret_cast<uint2*>(dst + (size_t)p * 256 + nb) = pk;
    }
  }
}

// ---------------- attention: split-F, all-f16, depth-2 prefetch, DPP pair-sum (frozen) ----------------
__launch_bounds__(256, 4)
__global__ void attn_kernel(const short* __restrict__ Qb, const short* __restrict__ Kb,
                            const short* __restrict__ Vb, const float* __restrict__ pos_emb,
                            short* __restrict__ ACC) {
  __shared__ unsigned pe16[25 * 128];   // packed f16 pairs, word-swizzled (0 conflicts)
  for (int i = threadIdx.x; i < 1600; i += 256) {
    float4 vv = reinterpret_cast<const float4*>(pos_emb)[i];
    int s = i >> 6;
    int jw = (i & 63) * 2;
    int e = ((jw >> 5) & 3) << 1;
    uint2 pk2;
    pk2.x = pkh(vv.x, vv.y);
    pk2.y = pkh(vv.z, vv.w);
    *reinterpret_cast<uint2*>(pe16 + s * 128 + (jw ^ e)) = pk2;
  }

  const int t = threadIdx.x;
  const int half = t & 1, h = (t >> 1) & 7, pl = t >> 4;
  const int id = blockIdx.x;
  const int b = id & 7;
  const int local = id >> 3;
  const int bx = local & 31, by = local >> 5;
  const int xx = bx * 4 + (pl & 3);
  const int yy = by * 4 + (pl >> 2);
  const int yc = min(max(yy, 2), 125), xc = min(max(xx, 2), 125);
  const int fo = h * 32 + half * 16;
  const size_t pbase = ((size_t)((b * 128 + yy) * 128 + xx)) * 256 + fo;
  const size_t cbase = ((size_t)((b * 128 + yc) * 128 + xc)) * 256 + fo;
  const float SCALE2 = 0.17677669529663689f * 1.4426950408889634f;  // rsqrt(32)*log2(e)

  uint4 qA = *reinterpret_cast<const uint4*>(Qb + pbase);
  uint4 qB = *reinterpret_cast<const uint4*>(Qb + pbase + 8);
  __syncthreads();

  float l = 0.f;
  __half2 oa[8];
#pragma unroll
  for (int jv = 0; jv < 8; ++jv) oa[jv] = uh2(0u);

  const short* kb = Kb + cbase;
  const short* vb = Vb + cbase;
  const int sw = h * 16 + half * 8;
  const int e = (h >> 1) << 1;

  uint4 k0a, k1a, v0a, v1a, k0b, k1b, v0b, v1b;
  {
    const short* kp = kb + (-2 * 128 - 2) * 256;
    const short* vp = vb + (-2 * 128 - 2) * 256;
    k0a = *reinterpret_cast<const uint4*>(kp);
    k1a = *reinterpret_cast<const uint4*>(kp + 8);
    v0a = *reinterpret_cast<const uint4*>(vp);
    v1a = *reinterpret_cast<const uint4*>(vp + 8);
    const short* kp1 = kb + (-2 * 128 - 1) * 256;
    const short* vp1 = vb + (-2 * 128 - 1) * 256;
    k0b = *reinterpret_cast<const uint4*>(kp1);
    k1b = *reinterpret_cast<const uint4*>(kp1 + 8);
    v0b = *reinterpret_cast<const uint4*>(vp1);
    v1b = *reinterpret_cast<const uint4*>(vp1 + 8);
  }

#pragma unroll 1
  for (int dy = -2; dy <= 2; ++dy) {
    const unsigned* prow = pe16 + ((dy + 2) * 5) * 128 + sw;
#pragma unroll
    for (int dxi = 0; dxi < 5; ++dxi) {
      const int dx = dxi - 2;
      uint4 k0 = k0a, k1 = k1a, v0 = v0a, v1 = v1a;
      k0a = k0b; k1a = k1b; v0a = v0b; v1a = v1b;
      int ndx = dx + 2, ndy = dy;
      if (ndx > 2) { ndx -= 5; ndy += 1; }
      if (ndy <= 2) {
        const short* kp2 = kb + (ndy * 128 + ndx) * 256;
        const short* vp2 = vb + (ndy * 128 + ndx) * 256;
        k0b = *reinterpret_cast<const uint4*>(kp2);
        k1b = *reinterpret_cast<const uint4*>(kp2 + 8);
        v0b = *reinterpret_cast<const uint4*>(vp2);
        v1b = *reinterpret_cast<const uint4*>(vp2 + 8);
      }
      const unsigned* ps = prow + dxi * 128;
      uint2 pp0 = *reinterpret_cast<const uint2*>(ps + (0 ^ e));
      uint2 pp1 = *reinterpret_cast<const uint2*>(ps + (2 ^ e));
      uint2 pp2 = *reinterpret_cast<const uint2*>(ps + (4 ^ e));
      uint2 pp3 = *reinterpret_cast<const uint2*>(ps + (6 ^ e));

      float d0 = 0.f, d1 = 0.f, d2 = 0.f, d3 = 0.f;
      d0 = fdot2u(qA.x, k0.x, d0); d1 = fdot2u(qA.y, k0.y, d1);
      d2 = fdot2u(qA.z, k0.z, d2); d3 = fdot2u(qA.w, k0.w, d3);
      d0 = fdot2u(qB.x, k1.x, d0); d1 = fdot2u(qB.y, k1.y, d1);
      d2 = fdot2u(qB.z, k1.z, d2); d3 = fdot2u(qB.w, k1.w, d3);
      d0 = fdot2u(qA.x, pp0.x, d0); d1 = fdot2u(qA.y, pp0.y, d1);
      d2 = fdot2u(qA.z, pp1.x, d2); d3 = fdot2u(qA.w, pp1.y, d3);
      d0 = fdot2u(qB.x, pp2.x, d0); d1 = fdot2u(qB.y, pp2.y, d1);
      d2 = fdot2u(qB.z, pp3.x, d2); d3 = fdot2u(qB.w, pp3.y, d3);

      float part = ((d0 + d1) + (d2 + d3)) * SCALE2;
      float full = pairsum(part);           // DPP quad_perm, no LDS round-trip
      float w = exp2f(full);
      l += w;
      __half2 w2 = uh2(pkh(w, w));
      oa[0] = __hfma2(w2, uh2(v0.x), oa[0]);
      oa[1] = __hfma2(w2, uh2(v0.y), oa[1]);
      oa[2] = __hfma2(w2, uh2(v0.z), oa[2]);
      oa[3] = __hfma2(w2, uh2(v0.w), oa[3]);
      oa[4] = __hfma2(w2, uh2(v1.x), oa[4]);
      oa[5] = __hfma2(w2, uh2(v1.y), oa[5]);
      oa[6] = __hfma2(w2, uh2(v1.z), oa[6]);
      oa[7] = __hfma2(w2, uh2(v1.w), oa[7]);
    }
  }

  float inv = 1.f / l;
  uint4 s0, s1;
  s0.x = cvtpk(__low2float(oa[0]) * inv, __high2float(oa[0]) * inv);
  s0.y = cvtpk(__low2float(oa[1]) * inv, __high2float(oa[1]) * inv);
  s0.z = cvtpk(__low2float(oa[2]) * inv, __high2float(oa[2]) * inv);
  s0.w = cvtpk(__low2float(oa[3]) * inv, __high2float(oa[3]) * inv);
  s1.x = cvtpk(__low2float(oa[4]) * inv, __high2float(oa[4]) * inv);
  s1.y = cvtpk(__low2float(oa[5]) * inv, __high2float(oa[5]) * inv);
  s1.z = cvtpk(__low2float(oa[6]) * inv, __high2float(oa[6]) * inv);
  s1.w = cvtpk(__low2float(oa[7]) * inv, __high2float(oa[7]) * inv);
  *reinterpret_cast<uint4*>(ACC + pbase) = s0;
  *reinterpret_cast<uint4*>(ACC + pbase + 8) = s1;
}

// ---------------- output projection: 256x256 tile + counted-vmcnt pipeline ----------------
__launch_bounds__(512, 2)
__global__ void out_gemm(const short* __restrict__ A, const short* __restrict__ WoT,
                         float* __restrict__ out) {
  __shared__ short As[2][256 * 64];
  __shared__ short Bs[2][256 * 64];
  const int t = threadIdx.x;
  const int bi = blockIdx.x;
  const int xcd = bi & 7;
  const int mt = xcd * 64 + (bi >> 3);
  const int m0 = mt * 256;
  const int wave = t >> 6, lane = t & 63;
  const int wm = (wave >> 2) * 128, wn = (wave & 3) * 64;
  const int lr = lane & 15, g = lane >> 4;

  const int ro = lane >> 3;
  const int colb = ((lane & 7) * 16) ^ (ro << 4);
  const char* aSrc0 = reinterpret_cast<const char*>(A + (size_t)(m0 + ro) * 256) + colb;
  const char* bSrc0 = reinterpret_cast<const char*>(WoT + (size_t)ro * 256) + colb;

  auto stage = [&](int buf, int ks) {
#pragma unroll
    for (int c = 0; c < 4; ++c) {
      int cc = wave * 4 + c;
      gld16(aSrc0 + (size_t)cc * 8 * 512 + ks * 128, (char*)As[buf] + cc * 1024);
      gld16(bSrc0 + (size_t)cc * 8 * 512 + ks * 128, (char*)Bs[buf] + cc * 1024);
    }
  };

  v4f acc[8][4];
#pragma unroll
  for (int i = 0; i < 8; ++i)
#pragma unroll
    for (int jj = 0; jj < 4; ++jj) acc[i][jj] = (v4f){0.f, 0.f, 0.f, 0.f};

  stage(0, 0);

#pragma unroll 1
  for (int s = 0; s < 4; ++s) {
    const int buf = s & 1;
    if (s < 3) {
      stage(buf ^ 1, s + 1);
      asm volatile("s_waitcnt vmcnt(8)" ::: "memory");
    } else {
      asm volatile("s_waitcnt vmcnt(0)" ::: "memory");
    }
    SBAR();
    SCHED0();

    const char* aB = (const char*)As[buf];
    const char* bB = (const char*)Bs[buf];
#pragma unroll
    for (int kk = 0; kk < 2; ++kk) {
      v8s bfr[4];
#pragma unroll
      for (int jj = 0; jj < 4; ++jj) {
        int rn = wn + jj * 16 + lr;
        bfr[jj] = *reinterpret_cast<const v8s*>(
            bB + ((rn * 128 + kk * 64 + g * 16) ^ ((rn & 7) << 4)));
      }
#pragma unroll
      for (int i = 0; i < 8; ++i) {
        int row = wm + i * 16 + lr;
        v8s af = *reinterpret_cast<const v8s*>(
            aB + ((row * 128 + kk * 64 + g * 16) ^ ((row & 7) << 4)));
#pragma unroll
        for (int jj = 0; jj < 4; ++jj)
          acc[i][jj] = __builtin_amdgcn_mfma_f32_16x16x32_bf16(bfr[jj], af, acc[i][jj], 0, 0, 0);
      }
    }
    if (s < 3) {
      asm volatile("s_waitcnt lgkmcnt(0)" ::: "memory");
      SBAR();
      SCHED0();
    }
  }

#pragma unroll
  for (int i = 0; i < 8; ++i) {
    int p = m0 + wm + i * 16 + lr;
#pragma unroll
    for (int jj = 0; jj < 4; ++jj) {
      int nb = wn + jj * 16 + g * 4;
      float4 o;
      o.x = acc[i][jj][0]; o.y = acc[i][jj][1];
      o.z = acc[i][jj][2]; o.w = acc[i][jj][3];
      *reinterpret_cast<float4*>(out + (size_t)p * 256 + nb) = o;
    }
  }
}

extern "C" void kernel_launch(void* const* d_in, const int* in_sizes, int n_in,
                              void* d_out, int out_size, void* d_ws, size_t ws_size,
                              hipStream_t stream) {
  const float* x       = (const float*)d_in[0];
  const float* Wq      = (const float*)d_in[1];
  const float* Wk      = (const float*)d_in[2];
  const float* Wv      = (const float*)d_in[3];
  const float* Wout    = (const float*)d_in[4];
  const float* pos_emb = (const float*)d_in[5];
  float* out = (float*)d_out;

  char* ws = (char*)d_ws;
  short* WcT  = (short*)ws;                       // 768*256*2   = 393216 B
  short* WoT  = (short*)(ws + 393216);            // 256*256*2   = 131072 B
  short* Qb   = (short*)(ws + 524288);            // 131072*256*2 each
  short* Kb   = Qb + (size_t)131072 * 256;
  short* Vb   = Kb + (size_t)131072 * 256;
  short* ACCb = Vb + (size_t)131072 * 256;
  short* xb   = ACCb;   // alias: xb used only before attn writes ACCb

  prep_weights<<<768, 256, 0, stream>>>(Wq, Wk, Wv, Wout, WcT, WoT);
  x_cast<<<4096, 256, 0, stream>>>(x, xb);
  proj_gemm<<<1536, 512, 0, stream>>>(xb, WcT, pos_emb, Qb, Kb, Vb);
  attn_kernel<<<8192, 256, 0, stream>>>(Qb, Kb, Vb, pos_emb, ACCb);
  out_gemm<<<512, 512, 0, stream>>>(ACCb, WoT, out);
}